// Round 13
// baseline (141.418 us; speedup 1.0000x reference)
//
#include <hip/hip_runtime.h>
#include <hip/hip_bf16.h>

// Problem constants
#define NB   8      // batch
#define NL   1024   // sequence length
#define ND   256    // model dim
#define NH   8      // heads
#define NHD  64     // head dim
#define NC   512    // NH*NHD
#define NTOK (NB*NL) // 8192

typedef __bf16 bf16x8v __attribute__((ext_vector_type(8)));
typedef float f32x4 __attribute__((ext_vector_type(4)));

__device__ __forceinline__ unsigned short f2bf(float f) {
  unsigned u = __float_as_uint(f);
  unsigned r = (u + 0x7fffu + ((u >> 16) & 1u)) >> 16;
  return (unsigned short)r;
}

// pack two f32 -> bf16x2 (elem0 in low 16 bits), RNE
__device__ __forceinline__ unsigned pack_bf16x2(float lo, float hi) {
  __hip_bfloat162 h2 = __float22bfloat162_rn(make_float2(lo, hi));
  union { __hip_bfloat162 h; unsigned u; } cvt;
  cvt.h = h2;
  return cvt.u;
}

// ---------------------------------------------------------------------------
// Fused QKV projection GEMM (prep folded in): grid (4 nt, 64 mt, 3 z)
// Reads x f32 + W f32 directly. A-tile: bf16(x + PE) on the fly (PE skipped
// for z==2/v). B-tile: W transposed on the fly (k-pair-packed b32 writes,
// slot-swizzled so the 16-lane scatter is 2-way/free). 128x128 tile, BK=64.
// Epilogue: z<2 direct (32B-grouped stores); z==2 LDS-transpose bounce ->
// fully coalesced dwordx4 row stores (fixes the 2B/2KB-stride scatter that
// made every wave-store 64 transactions).
// q folds attention scale AND log2(e) (softmax in exp2 domain).
// ---------------------------------------------------------------------------
__global__ __launch_bounds__(256) void gemm_qkv_fused_kernel(
    const float* __restrict__ x,
    const float* __restrict__ Wq, const float* __restrict__ Wk,
    const float* __restrict__ Wv,
    const float* __restrict__ bq, const float* __restrict__ bk,
    const float* __restrict__ bv,
    unsigned short* __restrict__ qg, unsigned short* __restrict__ kg,
    unsigned short* __restrict__ vg) {
  __shared__ unsigned short smem[2 * 128 * 72];   // As | Bs; reused as Ts
  unsigned short* As = smem;
  unsigned short* Bs = smem + 128 * 72;

  const int z = blockIdx.z;
  const float* Wsrc = (z == 0) ? Wq : (z == 1) ? Wk : Wv;
  const float* bias = (z == 0) ? bq : (z == 1) ? bk : bv;
  unsigned short* Out = (z == 0) ? qg : (z == 1) ? kg : vg;
  const float scale = (z == 0) ? 0.18033688011112042f : 1.0f;
  const bool addpe = (z < 2);

  const int nt = blockIdx.x;     // 0..3   N tile (128 cols)
  const int mt = blockIdx.y;     // 0..63  M tile (128 rows)
  const int tid = threadIdx.x;
  const int w = tid >> 6;
  const int wm = w >> 1, wn = w & 1;
  const int lane = tid & 63;
  const int lg = lane >> 4, lr = lane & 15;

  // A staging geometry: rows r0+32i, 8 k-elems at c8*8, slot-swizzled base.
  const int r0 = tid >> 3, c8 = tid & 7;
  unsigned short* Adst = As + r0 * 72 + 8 * ((c8 + 2 * (r0 & 7)) & 7);
  const float* xbase = x + (size_t)(mt * 128 + r0) * ND + c8 * 8;
  // B staging geometry: thread covers k-pairs kp0,kp0+16 x 8 n at no*8.
  const int no = tid & 15, kp0 = tid >> 4;

  f32x4 acc[4][4] = {};

  for (int kb = 0; kb < 4; ++kb) {
    if (kb) __syncthreads();
    // ---- A staging: bf16(x + PE) ----
    float i0 = 0.f, i1 = 0.f, i2 = 0.f, i3 = 0.f;
    if (addpe) {
      int dh = kb * 32 + c8 * 4;   // d>>1 for this thread's 4 sin/cos pairs
      i0 = __expf(-0.07195578415606394f * (float)(dh));
      i1 = __expf(-0.07195578415606394f * (float)(dh + 1));
      i2 = __expf(-0.07195578415606394f * (float)(dh + 2));
      i3 = __expf(-0.07195578415606394f * (float)(dh + 3));
    }
#pragma unroll
    for (int i = 0; i < 4; ++i) {
      int row = r0 + 32 * i;
      f32x4 xa = *(const f32x4*)(xbase + (size_t)(32 * i) * ND + kb * 64);
      f32x4 xc = *(const f32x4*)(xbase + (size_t)(32 * i) * ND + kb * 64 + 4);
      unsigned p0, p1, p2, p3;
      if (addpe) {
        float l = (float)((mt * 128 + row) & (NL - 1));
        float a0 = l * i0, a1 = l * i1, a2 = l * i2, a3 = l * i3;
        p0 = pack_bf16x2(xa[0] + __sinf(a0), xa[1] + __cosf(a0));
        p1 = pack_bf16x2(xa[2] + __sinf(a1), xa[3] + __cosf(a1));
        p2 = pack_bf16x2(xc[0] + __sinf(a2), xc[1] + __cosf(a2));
        p3 = pack_bf16x2(xc[2] + __sinf(a3), xc[3] + __cosf(a3));
      } else {
        p0 = pack_bf16x2(xa[0], xa[1]);
        p1 = pack_bf16x2(xa[2], xa[3]);
        p2 = pack_bf16x2(xc[0], xc[1]);
        p3 = pack_bf16x2(xc[2], xc[3]);
      }
      int4 pv; pv.x = (int)p0; pv.y = (int)p1; pv.z = (int)p2; pv.w = (int)p3;
      *(int4*)(Adst + (size_t)(32 * i) * 72) = pv;
    }
    // ---- B staging: transpose W f32 -> Bs[n][k] bf16 (k-pairs, b32) ----
#pragma unroll
    for (int u = 0; u < 2; ++u) {
      int kp = kp0 + 16 * u;                 // k-pair index 0..31
      int krow = kb * 64 + 2 * kp;
      const float* wr0 = Wsrc + (size_t)krow * NC + nt * 128 + no * 8;
      const float* wr1 = wr0 + NC;
      f32x4 w0a = *(const f32x4*)(wr0);
      f32x4 w0b = *(const f32x4*)(wr0 + 4);
      f32x4 w1a = *(const f32x4*)(wr1);
      f32x4 w1b = *(const f32x4*)(wr1 + 4);
#pragma unroll
      for (int e = 0; e < 8; ++e) {
        float lo = (e < 4) ? w0a[e] : w0b[e - 4];
        float hi = (e < 4) ? w1a[e] : w1b[e - 4];
        int n = no * 8 + e;
        *(unsigned*)(Bs + n * 72 + 8 * (((kp >> 2) + (no & 7)) & 7) +
                     (kp & 3) * 2) = pack_bf16x2(lo, hi);
      }
    }
    __syncthreads();

    // ---- MFMA (swizzled LDS reads, matching staging) ----
#pragma unroll
    for (int kk = 0; kk < 2; ++kk) {
      bf16x8v a[4], b[4];
#pragma unroll
      for (int mi = 0; mi < 4; ++mi) {
        int row = wm * 64 + mi * 16 + lr;
        a[mi] = *(const bf16x8v*)(As + row * 72 +
                                  8 * ((4 * kk + lg + 2 * (row & 7)) & 7));
      }
#pragma unroll
      for (int nj = 0; nj < 4; ++nj) {
        int n = wn * 64 + nj * 16 + lr;
        b[nj] = *(const bf16x8v*)(Bs + n * 72 +
                                  8 * ((4 * kk + lg + ((n >> 3) & 7)) & 7));
      }
#pragma unroll
      for (int mi = 0; mi < 4; ++mi)
#pragma unroll
        for (int nj = 0; nj < 4; ++nj)
          acc[mi][nj] = __builtin_amdgcn_mfma_f32_16x16x32_bf16(
              a[mi], b[nj], acc[mi][nj], 0, 0, 0);
    }
  }

  // C row = (lane>>4)*4 + j, col = lane&15  [HW-verified layout]
  const float bval = bias[nt * 2 + wn];
  const int h = nt * 2 + wn;
  if (z < 2) {
    // Direct store: 16 consecutive lr lanes -> 32B contiguous groups.
#pragma unroll
    for (int mi = 0; mi < 4; ++mi) {
#pragma unroll
      for (int nj = 0; nj < 4; ++nj) {
#pragma unroll
        for (int j = 0; j < 4; ++j) {
          int r = mt * 128 + wm * 64 + mi * 16 + lg * 4 + j;   // token index
          int dd = nj * 16 + lr;                               // dim in head
          int bb = r >> 10, lpos = r & (NL - 1);
          float val = (acc[mi][nj][j] + bval) * scale;
          Out[((bb * NH + h) * NL + lpos) * NHD + dd] = f2bf(val);
        }
      }
    }
  } else {
    // V: LDS-transpose bounce -> coalesced row stores.
    __syncthreads();                       // MFMA LDS reads complete
    unsigned short* Ts = smem;             // 128 (dd) x 136 (r_local)
#pragma unroll
    for (int mi = 0; mi < 4; ++mi)
#pragma unroll
      for (int nj = 0; nj < 4; ++nj)
#pragma unroll
        for (int jp = 0; jp < 2; ++jp) {
          int c = wn * 64 + nj * 16 + lr;              // dd 0..127
          int r = wm * 64 + mi * 16 + lg * 4 + jp * 2; // even r_local
          *(unsigned*)(Ts + c * 136 + r) =
              pack_bf16x2(acc[mi][nj][jp * 2] + bval,
                          acc[mi][nj][jp * 2 + 1] + bval);
        }
    __syncthreads();
    int row = tid >> 1, half = tid & 1;    // dd-row 0..127, 128B half
    int hh = nt * 2 + (row >> 6);
    int ddl = row & 63;
    int bb2 = (mt * 128) >> 10;
    int lpos0 = (mt * 128) & (NL - 1);
    unsigned short* dst =
        Out + ((size_t)(bb2 * NH + hh) * NHD + ddl) * NL + lpos0 + half * 64;
    const unsigned short* src = Ts + row * 136 + half * 64;
#pragma unroll
    for (int i = 0; i < 8; ++i)
      *(int4*)(dst + i * 8) = *(const int4*)(src + i * 8);
  }
}

// ---------------------------------------------------------------------------
// Flash attention (round-10 proven version): swapped-operand + exp2-domain +
// defer-max + named-temp double-buffered staging + tree reductions + setprio.
// Linear +72-pad LDS addressing (the 5.77M "bank conflict" count is a fixed
// per-b128-op phase cost, not fixable by swizzle -- measured r10 vs r11).
// ---------------------------------------------------------------------------
__global__ __launch_bounds__(256) void attn_kernel(
    const unsigned short* __restrict__ Q,
    const unsigned short* __restrict__ K,
    const unsigned short* __restrict__ Vt,
    float* __restrict__ Out) {
  __shared__ unsigned short Ks[64 * 72];
  __shared__ unsigned short Vs[64 * 72];
  __shared__ unsigned short Ps[64 * 72];

  const int qt = blockIdx.x;   // 0..15
  const int bh = blockIdx.y;   // 0..63
  const int bb = bh >> 3, h = bh & 7;
  const int tid = threadIdx.x;
  const int w = tid >> 6;
  const int lane = tid & 63;
  const int lg = lane >> 4, lr = lane & 15;
  const int qrow0 = qt * 64 + w * 16;

  // Q B-fragment: row = lr, k-slice = lg*8 within each 32-block
  bf16x8v qf[2];
#pragma unroll
  for (int kk = 0; kk < 2; ++kk)
    qf[kk] = *(const bf16x8v*)(Q + ((size_t)bh * NL + qrow0 + lr) * NHD + kk * 32 + lg * 8);

  // Per-thread staging geometry: rows r0 and r0+32, fixed 16B column c8o.
  const int r0 = tid >> 3;
  const int c8o = (tid & 7) * 8;
  const unsigned short* kp0 = K + (size_t)bh * NL * NHD + r0 * NHD + c8o;   // +kv*64*NHD
  const unsigned short* vp0 = Vt + ((size_t)bh * NHD + r0) * NL + c8o;      // +kv*64
  unsigned short* kdst = Ks + r0 * 72 + c8o;
  unsigned short* vdst = Vs + r0 * 72 + c8o;

  float m_ = -1e30f, lsum = 0.0f;
  f32x4 o[4] = {};
  int4 ka, kc, va, vc;

#define KVLOADS(kv)                                             \
  ka = *(const int4*)(kp0 + (kv) * 64 * NHD);                   \
  kc = *(const int4*)(kp0 + (kv) * 64 * NHD + 32 * NHD);        \
  va = *(const int4*)(vp0 + (kv) * 64);                         \
  vc = *(const int4*)(vp0 + (kv) * 64 + 32 * NL);

  KVLOADS(0)
  for (int kv = 0; kv < 16; ++kv) {
    if (kv) __syncthreads();          // all waves done with previous tile
    *(int4*)(kdst)           = ka;
    *(int4*)(kdst + 32 * 72) = kc;
    *(int4*)(vdst)           = va;
    *(int4*)(vdst + 32 * 72) = vc;
    if (kv < 15) { KVLOADS(kv + 1) }  // next tile loads fly during compute
    __syncthreads();

    // S^T = K * Q^T (log2 units; scale*log2e folded into Q)
    f32x4 s[4] = {};
    __builtin_amdgcn_s_setprio(1);
#pragma unroll
    for (int kk = 0; kk < 2; ++kk) {
#pragma unroll
      for (int nb = 0; nb < 4; ++nb) {
        bf16x8v kf = *(const bf16x8v*)(Ks + (nb * 16 + lr) * 72 + kk * 32 + lg * 8);
        s[nb] = __builtin_amdgcn_mfma_f32_16x16x32_bf16(kf, qf[kk], s[nb], 0, 0, 0);
      }
    }
    __builtin_amdgcn_s_setprio(0);

    // Online softmax, exp2 domain, defer-max (wave-uniform rescale decision)
    float tm;
    {
      float a0 = fmaxf(s[0][0], s[0][1]), a1 = fmaxf(s[0][2], s[0][3]);
      float a2 = fmaxf(s[1][0], s[1][1]), a3 = fmaxf(s[1][2], s[1][3]);
      float a4 = fmaxf(s[2][0], s[2][1]), a5 = fmaxf(s[2][2], s[2][3]);
      float a6 = fmaxf(s[3][0], s[3][1]), a7 = fmaxf(s[3][2], s[3][3]);
      float c0 = fmaxf(fmaxf(a0, a1), fmaxf(a2, a3));
      float c1 = fmaxf(fmaxf(a4, a5), fmaxf(a6, a7));
      tm = fmaxf(c0, c1);
    }
    tm = fmaxf(tm, __shfl_xor(tm, 16, 64));
    tm = fmaxf(tm, __shfl_xor(tm, 32, 64));
    if (__any(tm > m_ + 8.0f)) {
      float nm = fmaxf(m_, tm);
      float corr = exp2f(m_ - nm);
      m_ = nm;
      lsum *= corr;
#pragma unroll
      for (int db = 0; db < 4; ++db)
#pragma unroll
        for (int j = 0; j < 4; ++j) o[db][j] *= corr;
    }
#pragma unroll
    for (int nb = 0; nb < 4; ++nb)
#pragma unroll
      for (int j = 0; j < 4; ++j)
        s[nb][j] = exp2f(s[nb][j] - m_);
    float ts;
    {
      float a0 = s[0][0] + s[0][1], a1 = s[0][2] + s[0][3];
      float a2 = s[1][0] + s[1][1], a3 = s[1][2] + s[1][3];
      float a4 = s[2][0] + s[2][1], a5 = s[2][2] + s[2][3];
      float a6 = s[3][0] + s[3][1], a7 = s[3][2] + s[3][3];
      ts = ((a0 + a1) + (a2 + a3)) + ((a4 + a5) + (a6 + a7));
    }
    ts += __shfl_xor(ts, 16, 64);
    ts += __shfl_xor(ts, 32, 64);
    lsum += ts;

    // P row q=lr -> LDS packed u32 (wave-private rows; no barrier needed)
#pragma unroll
    for (int nb = 0; nb < 4; ++nb)
#pragma unroll
      for (int hh = 0; hh < 2; ++hh)
        *(unsigned*)(Ps + (w * 16 + lr) * 72 + nb * 16 + lg * 4 + 2 * hh) =
            pack_bf16x2(s[nb][2 * hh], s[nb][2 * hh + 1]);

    // O^T += V^T * P^T
    __builtin_amdgcn_s_setprio(1);
#pragma unroll
    for (int kk = 0; kk < 2; ++kk) {
      bf16x8v pf = *(const bf16x8v*)(Ps + (w * 16 + lr) * 72 + kk * 32 + lg * 8);
#pragma unroll
      for (int db = 0; db < 4; ++db) {
        bf16x8v vf = *(const bf16x8v*)(Vs + (db * 16 + lr) * 72 + kk * 32 + lg * 8);
        o[db] = __builtin_amdgcn_mfma_f32_16x16x32_bf16(vf, pf, o[db], 0, 0, 0);
      }
    }
    __builtin_amdgcn_s_setprio(0);
  }
#undef KVLOADS

  // Normalize (scalar per lane) and write out[B, L, 512] f32 as float4s
  float inv = 1.0f / lsum;
  int q = qrow0 + lr;
#pragma unroll
  for (int db = 0; db < 4; ++db) {
    f32x4 ov;
#pragma unroll
    for (int j = 0; j < 4; ++j) ov[j] = o[db][j] * inv;
    *(f32x4*)(Out + (size_t)(bb * NL + q) * NC + h * NHD + db * 16 + lg * 4) = ov;
  }
}

// ---------------------------------------------------------------------------
extern "C" void kernel_launch(void* const* d_in, const int* in_sizes, int n_in,
                              void* d_out, int out_size, void* d_ws, size_t ws_size,
                              hipStream_t stream) {
  const float* x  = (const float*)d_in[0];
  const float* Wq = (const float*)d_in[1];
  const float* bq = (const float*)d_in[2];
  const float* Wk = (const float*)d_in[3];
  const float* bk = (const float*)d_in[4];
  const float* Wv = (const float*)d_in[5];
  const float* bv = (const float*)d_in[6];
  float* out = (float*)d_out;

  // Workspace: q/k/v bf16 buffers (8 MB each)
  unsigned short* qg = (unsigned short*)d_ws;
  unsigned short* kg = qg + (size_t)NB * NH * NL * NHD;
  unsigned short* vg = kg + (size_t)NB * NH * NL * NHD;

  gemm_qkv_fused_kernel<<<dim3(4, 64, 3), 256, 0, stream>>>(
      x, Wq, Wk, Wv, bq, bk, bv, qg, kg, vg);

  attn_kernel<<<dim3(16, 64), 256, 0, stream>>>(qg, kg, vg, out);
}